// Round 1
// baseline (2133.706 us; speedup 1.0000x reference)
//
#include <hip/hip_runtime.h>
#include <hip/hip_bf16.h>
#include <stdint.h>

// Problem constants
#define B_DIM 4
#define L_DIM 2048
#define D_DIM 768
#define DI_DIM 1536
#define DS_DIM 16
#define DR_DIM 48

typedef __attribute__((ext_vector_type(8))) short bf16x8;   // 8 bf16 = 4 VGPRs (MFMA A/B frag)
typedef __attribute__((ext_vector_type(4))) float f32x4;    // MFMA C/D frag

__device__ inline float bf2f(ushort h) {
    union { uint32_t u; float f; } x; x.u = ((uint32_t)h) << 16; return x.f;
}
__device__ inline ushort f2bf(float f) {
    union { float f; uint32_t u; } x; x.f = f;
    uint32_t r = x.u + 0x7fffu + ((x.u >> 16) & 1u);  // RNE
    return (ushort)(r >> 16);
}
__device__ inline float sigmoidf_(float v) { return 1.f / (1.f + __expf(-v)); }

// ---------------------------------------------------------------------------
// ada = silu(c) @ ada_w.T + ada_b  -> shift/scale/gate  (each [B,768] f32)
// grid: 2304 blocks x 256 (4 waves; wave computes one output j)
// ---------------------------------------------------------------------------
__global__ __launch_bounds__(256) void ada_kernel(
    const float* __restrict__ c, const float* __restrict__ ada_w,
    const float* __restrict__ ada_b,
    float* __restrict__ shiftb, float* __restrict__ scaleb, float* __restrict__ gateb)
{
    __shared__ float lc[2 * D_DIM];  // silu(c[b,:]), 1536 floats
    int b = blockIdx.x / 576;
    int jbase = (blockIdx.x % 576) * 4;
    int tid = threadIdx.x;
    for (int k = tid; k < 2 * D_DIM; k += 256) {
        float cv = c[b * 2 * D_DIM + k];
        lc[k] = cv * sigmoidf_(cv);
    }
    __syncthreads();
    int wave = tid >> 6, lane = tid & 63;
    int j = jbase + wave;
    const float4* wrow = reinterpret_cast<const float4*>(ada_w + (size_t)j * (2 * D_DIM));
    const float4* lc4 = reinterpret_cast<const float4*>(lc);
    float acc = 0.f;
#pragma unroll
    for (int i = 0; i < 6; ++i) {
        float4 w = wrow[lane + 64 * i];
        float4 a = lc4[lane + 64 * i];
        acc += a.x * w.x + a.y * w.y + a.z * w.z + a.w * w.w;
    }
#pragma unroll
    for (int off = 32; off >= 1; off >>= 1) acc += __shfl_xor(acc, off);
    if (lane == 0) {
        acc += ada_b[j];
        if (j < 768)       shiftb[b * 768 + j] = acc;
        else if (j < 1536) scaleb[b * 768 + (j - 768)] = acc;
        else               gateb[b * 768 + (j - 1536)] = acc;
    }
}

// ---------------------------------------------------------------------------
// Generic f32 -> bf16 cast with zero padding.
// dst[r*Cd+c] = (r<Rs && c<Cs) ? src[r*src_ld+c] : 0
// ---------------------------------------------------------------------------
__global__ void cast_pad_kernel(const float* __restrict__ src, ushort* __restrict__ dst,
                                int Rd, int Cd, int Rs, int Cs, int src_ld)
{
    int gid = blockIdx.x * 256 + threadIdx.x;
    if (gid >= Rd * Cd) return;
    int r = gid / Cd, cc = gid % Cd;
    float v = (r < Rs && cc < Cs) ? src[(size_t)r * src_ld + cc] : 0.f;
    dst[gid] = f2bf(v);
}

// ---------------------------------------------------------------------------
// LayerNorm + AdaLN modulation -> xm (bf16, [8192,768])
// one block per row
// ---------------------------------------------------------------------------
__global__ __launch_bounds__(256) void ln_mod_kernel(
    const float* __restrict__ x, const float* __restrict__ ln_w, const float* __restrict__ ln_b,
    const float* __restrict__ shiftb, const float* __restrict__ scaleb, ushort* __restrict__ xmb)
{
    int row = blockIdx.x;          // b*2048 + l
    int bb = row >> 11;
    int tid = threadIdx.x;
    const float* xr = x + (size_t)row * D_DIM;
    float v0 = xr[tid], v1 = xr[tid + 256], v2 = xr[tid + 512];
    float s1 = v0 + v1 + v2;
    float s2 = v0 * v0 + v1 * v1 + v2 * v2;
#pragma unroll
    for (int off = 32; off >= 1; off >>= 1) { s1 += __shfl_xor(s1, off); s2 += __shfl_xor(s2, off); }
    __shared__ float red[8];
    int wave = tid >> 6, lane = tid & 63;
    if (lane == 0) { red[wave] = s1; red[4 + wave] = s2; }
    __syncthreads();
    s1 = red[0] + red[1] + red[2] + red[3];
    s2 = red[4] + red[5] + red[6] + red[7];
    float mu = s1 * (1.f / 768.f);
    float var = s2 * (1.f / 768.f) - mu * mu;
    float rs = rsqrtf(var + 1e-5f);
    const float* sh = shiftb + bb * D_DIM;
    const float* sc = scaleb + bb * D_DIM;
    ushort* orow = xmb + (size_t)row * D_DIM;
#pragma unroll
    for (int r = 0; r < 3; ++r) {
        int j = tid + r * 256;
        float xv = (r == 0 ? v0 : (r == 1 ? v1 : v2));
        float xn = (xv - mu) * rs * ln_w[j] + ln_b[j];
        orow[j] = f2bf(xn * (1.f + sc[j]) + sh[j]);
    }
}

// ---------------------------------------------------------------------------
// bf16 MFMA GEMM:  C[M,N] = A[M,K] @ B[N,K]^T   (both row-major, K-contig)
// 128x128 tile, 256 threads = 4 waves (2x2), each wave 4x4 subtiles of 16x16.
// Requires M%128==0, N%128==0, K%32==0.  Epilogue modes:
//   0: bf16 store            (xz)
//   1: f32 store, col<Nstore (dbl, ldc=80)
//   2: bf16 softplus(acc + aux0[col])          (delta)
//   3: f32  aux0[row*ldc+col] + aux1[(row>>11)*ldc+col]*acc   (final out)
// ---------------------------------------------------------------------------
__global__ __launch_bounds__(256, 2) void gemm_bt_kernel(
    const ushort* __restrict__ A, const ushort* __restrict__ B,
    int M, int N, int K,
    int mode, void* __restrict__ Cout, int ldc, int Nstore,
    const float* __restrict__ aux0, const float* __restrict__ aux1)
{
    __shared__ ushort ldsA[128 * 40];  // row stride 40 (pad 8) -> 2-way-free banks
    __shared__ ushort ldsB[128 * 40];
    int m0 = blockIdx.x * 128, n0 = blockIdx.y * 128;
    int tid = threadIdx.x;
    int wave = tid >> 6, lane = tid & 63;
    int wr = wave >> 1, wc = wave & 1;
    int quad = lane >> 4, lr = lane & 15;

    f32x4 zero4 = {0.f, 0.f, 0.f, 0.f};
    f32x4 acc[4][4];
#pragma unroll
    for (int i = 0; i < 4; ++i)
#pragma unroll
        for (int j = 0; j < 4; ++j) acc[i][j] = zero4;

    for (int k0 = 0; k0 < K; k0 += 32) {
        __syncthreads();
#pragma unroll
        for (int rr = 0; rr < 2; ++rr) {
            int c = tid + rr * 256;       // 0..511
            int row = c >> 2, kp = c & 3; // 4x16B chunks per row of 32 bf16
            uint4 va = *reinterpret_cast<const uint4*>(A + (size_t)(m0 + row) * K + k0 + kp * 8);
            *reinterpret_cast<uint4*>(&ldsA[row * 40 + kp * 8]) = va;
            uint4 vb = *reinterpret_cast<const uint4*>(B + (size_t)(n0 + row) * K + k0 + kp * 8);
            *reinterpret_cast<uint4*>(&ldsB[row * 40 + kp * 8]) = vb;
        }
        __syncthreads();
        bf16x8 af[4], bfr[4];
#pragma unroll
        for (int i = 0; i < 4; ++i)
            af[i] = *reinterpret_cast<const bf16x8*>(&ldsA[(wr * 64 + i * 16 + lr) * 40 + quad * 8]);
#pragma unroll
        for (int j = 0; j < 4; ++j)
            bfr[j] = *reinterpret_cast<const bf16x8*>(&ldsB[(wc * 64 + j * 16 + lr) * 40 + quad * 8]);
#pragma unroll
        for (int i = 0; i < 4; ++i)
#pragma unroll
            for (int j = 0; j < 4; ++j)
                acc[i][j] = __builtin_amdgcn_mfma_f32_16x16x32_bf16(af[i], bfr[j], acc[i][j], 0, 0, 0);
    }

    // epilogue: C/D layout col=lane&15, row=quad*4+reg  [m89-verified]
#pragma unroll
    for (int i = 0; i < 4; ++i) {
#pragma unroll
        for (int j = 0; j < 4; ++j) {
#pragma unroll
            for (int r = 0; r < 4; ++r) {
                int grow = m0 + wr * 64 + i * 16 + quad * 4 + r;
                int gcol = n0 + wc * 64 + j * 16 + lr;
                float v = acc[i][j][r];
                if (mode == 0) {
                    ((ushort*)Cout)[(size_t)grow * ldc + gcol] = f2bf(v);
                } else if (mode == 1) {
                    if (gcol < Nstore) ((float*)Cout)[(size_t)grow * ldc + gcol] = v;
                } else if (mode == 2) {
                    float t = v + aux0[gcol];
                    float sp = (t > 20.f) ? t : log1pf(__expf(t));
                    ((ushort*)Cout)[(size_t)grow * ldc + gcol] = f2bf(sp);
                } else {
                    int bb = grow >> 11;
                    ((float*)Cout)[(size_t)grow * ldc + gcol] =
                        aux0[(size_t)grow * ldc + gcol] + aux1[bb * ldc + gcol] * v;
                }
            }
        }
    }
}

// ---------------------------------------------------------------------------
// depthwise causal conv (K=4) + bias + silu -> u (bf16 [8192,1536])
// xi = xz[:, :, 0:1536]
// ---------------------------------------------------------------------------
__global__ void conv_silu_kernel(const ushort* __restrict__ xz, const float* __restrict__ conv_w,
                                 const float* __restrict__ conv_b, ushort* __restrict__ u)
{
    int gid = blockIdx.x * 256 + threadIdx.x;   // < 12582912
    int ch = gid % DI_DIM;
    int bl = gid / DI_DIM;
    int l = bl & (L_DIM - 1);
    int bb = bl >> 11;
    float acc = conv_b[ch];
#pragma unroll
    for (int k = 0; k < 4; ++k) {
        int ll = l - 3 + k;
        if (ll >= 0)
            acc += bf2f(xz[((size_t)bb * L_DIM + ll) * 3072 + ch]) * conv_w[ch * 4 + k];
    }
    u[(size_t)bl * DI_DIM + ch] = f2bf(acc * sigmoidf_(acc));
}

// ---------------------------------------------------------------------------
// selective scan.  grid 384 x 64.  thread <-> (b, d, 4 states)
// reads delta,u (bf16), B/C from dbl (f32, cols 48..79), z from xz col 1536+d
// writes y_out = (scan_y + u*D) * silu(z)  as bf16
// ---------------------------------------------------------------------------
__global__ __launch_bounds__(64) void scan_kernel(
    const ushort* __restrict__ delta, const ushort* __restrict__ u,
    const ushort* __restrict__ xz, const float* __restrict__ dbl,
    const float* __restrict__ A_log, const float* __restrict__ D_param,
    ushort* __restrict__ ybuf)
{
    int lane = threadIdx.x;
    int g = blockIdx.x * 64 + lane;
    int dg = g >> 2, sub = g & 3;
    int b = dg / DI_DIM, d = dg % DI_DIM;
    float Ad[4];
#pragma unroll
    for (int k = 0; k < 4; ++k) Ad[k] = -__expf(A_log[d * DS_DIM + sub * 4 + k]);
    float Dp = D_param[d];
    float h[4] = {0.f, 0.f, 0.f, 0.f};
    __shared__ float lsB[16][16];
    __shared__ float lsC[16][16];
    const size_t baseBL = (size_t)b * L_DIM;

    for (int l0 = 0; l0 < L_DIM; l0 += 16) {
        __syncthreads();
        {
            int li = lane >> 2, c4 = lane & 3;
            const float* src = dbl + (baseBL + l0 + li) * 80 + 48;
            float4 vB = *reinterpret_cast<const float4*>(src + c4 * 4);
            float4 vC = *reinterpret_cast<const float4*>(src + 16 + c4 * 4);
            lsB[li][c4 * 4 + 0] = vB.x; lsB[li][c4 * 4 + 1] = vB.y;
            lsB[li][c4 * 4 + 2] = vB.z; lsB[li][c4 * 4 + 3] = vB.w;
            lsC[li][c4 * 4 + 0] = vC.x; lsC[li][c4 * 4 + 1] = vC.y;
            lsC[li][c4 * 4 + 2] = vC.z; lsC[li][c4 * 4 + 3] = vC.w;
        }
        __syncthreads();
#pragma unroll
        for (int li = 0; li < 16; ++li) {
            int l = l0 + li;
            size_t idx = (baseBL + l) * DI_DIM + d;
            float dt = bf2f(delta[idx]);
            float ut = bf2f(u[idx]);
            float zt = bf2f(xz[(baseBL + l) * 3072 + DI_DIM + d]);
            float du = dt * ut;
            float yp = 0.f;
#pragma unroll
            for (int k = 0; k < 4; ++k) {
                float dA = __expf(dt * Ad[k]);
                h[k] = dA * h[k] + du * lsB[li][sub * 4 + k];
                yp += h[k] * lsC[li][sub * 4 + k];
            }
            yp += __shfl_xor(yp, 1);
            yp += __shfl_xor(yp, 2);
            if (sub == 0) {
                float yy = (yp + ut * Dp) * (zt * sigmoidf_(zt));
                ybuf[idx] = f2bf(yy);
            }
        }
    }
}

// ---------------------------------------------------------------------------
extern "C" void kernel_launch(void* const* d_in, const int* in_sizes, int n_in,
                              void* d_out, int out_size, void* d_ws, size_t ws_size,
                              hipStream_t stream) {
    (void)in_sizes; (void)n_in; (void)out_size;
    const float* x         = (const float*)d_in[0];
    const float* c         = (const float*)d_in[1];
    const float* ln_w      = (const float*)d_in[2];
    const float* ln_b      = (const float*)d_in[3];
    const float* ada_w     = (const float*)d_in[4];
    const float* ada_b     = (const float*)d_in[5];
    const float* in_proj_w = (const float*)d_in[6];
    const float* conv_w    = (const float*)d_in[7];
    const float* conv_b    = (const float*)d_in[8];
    const float* x_proj_w  = (const float*)d_in[9];
    const float* dt_proj_w = (const float*)d_in[10];
    const float* dt_proj_b = (const float*)d_in[11];
    const float* A_log     = (const float*)d_in[12];
    const float* D_param   = (const float*)d_in[13];
    const float* out_proj_w= (const float*)d_in[14];

    char* base = (char*)d_ws;
    size_t off = 0;
    auto alloc = [&](size_t bytes) { size_t o = off; off = (off + bytes + 255) & ~(size_t)255; return o; };
    const size_t R = (size_t)B_DIM * L_DIM;           // 8192 rows

    size_t o_shift = alloc(B_DIM * D_DIM * 4);
    size_t o_scale = alloc(B_DIM * D_DIM * 4);
    size_t o_gate  = alloc(B_DIM * D_DIM * 4);
    size_t o_xmb   = alloc(R * D_DIM * 2);            // bf16 xm
    size_t o_w1b   = alloc((size_t)3072 * 768 * 2);   // in_proj bf16
    size_t o_w2b   = alloc((size_t)768 * 1536 * 2);   // out_proj bf16
    size_t o_xwb   = alloc((size_t)128 * 1536 * 2);   // x_proj bf16, N-padded 80->128
    size_t o_dtwb  = alloc((size_t)1536 * 64 * 2);    // dt_proj bf16, K-padded 48->64
    size_t o_xzb   = alloc(R * 3072 * 2);             // xz bf16
    size_t o_ub    = alloc(R * DI_DIM * 2);           // u bf16
    size_t o_dbl   = alloc(R * 80 * 4);               // dbl f32
    size_t o_dtb   = alloc(R * 64 * 2);               // dt bf16, K-padded
    size_t o_delta = alloc(R * DI_DIM * 2);           // delta bf16
    size_t o_yb    = alloc(R * DI_DIM * 2);           // y bf16
    if (ws_size < off) return;  // workspace too small -> visible as stub-level absmax

    float*  shiftb = (float*)(base + o_shift);
    float*  scaleb = (float*)(base + o_scale);
    float*  gateb  = (float*)(base + o_gate);
    ushort* xmb    = (ushort*)(base + o_xmb);
    ushort* w1b    = (ushort*)(base + o_w1b);
    ushort* w2b    = (ushort*)(base + o_w2b);
    ushort* xwb    = (ushort*)(base + o_xwb);
    ushort* dtwb   = (ushort*)(base + o_dtwb);
    ushort* xzb    = (ushort*)(base + o_xzb);
    ushort* ub     = (ushort*)(base + o_ub);
    float*  dbl    = (float*)(base + o_dbl);
    ushort* dtb    = (ushort*)(base + o_dtb);
    ushort* deltab = (ushort*)(base + o_delta);
    ushort* yb     = (ushort*)(base + o_yb);

    auto cdiv = [](size_t a, size_t b) { return (int)((a + b - 1) / b); };

    // 1. ada -> shift/scale/gate
    ada_kernel<<<2304, 256, 0, stream>>>(c, ada_w, ada_b, shiftb, scaleb, gateb);
    // 2. weight casts
    cast_pad_kernel<<<cdiv(3072 * 768, 256), 256, 0, stream>>>(in_proj_w, w1b, 3072, 768, 3072, 768, 768);
    cast_pad_kernel<<<cdiv(768 * 1536, 256), 256, 0, stream>>>(out_proj_w, w2b, 768, 1536, 768, 1536, 1536);
    cast_pad_kernel<<<cdiv(128 * 1536, 256), 256, 0, stream>>>(x_proj_w, xwb, 128, 1536, 80, 1536, 1536);
    cast_pad_kernel<<<cdiv(1536 * 64, 256), 256, 0, stream>>>(dt_proj_w, dtwb, 1536, 64, 1536, 48, 48);
    // 3. LayerNorm + modulation -> xm bf16
    ln_mod_kernel<<<(int)R, 256, 0, stream>>>(x, ln_w, ln_b, shiftb, scaleb, xmb);
    // 4. xz = xm @ in_proj_w^T   [8192 x 3072]
    gemm_bt_kernel<<<dim3(64, 24), 256, 0, stream>>>(xmb, w1b, (int)R, 3072, 768,
                                                     0, xzb, 3072, 3072, nullptr, nullptr);
    // 5. depthwise conv + silu -> u
    conv_silu_kernel<<<cdiv(R * DI_DIM, 256), 256, 0, stream>>>(xzb, conv_w, conv_b, ub);
    // 6. dbl = u @ x_proj_w^T    [8192 x 80]  (N padded to 128)
    gemm_bt_kernel<<<dim3(64, 1), 256, 0, stream>>>(ub, xwb, (int)R, 128, 1536,
                                                    1, dbl, 80, 80, nullptr, nullptr);
    // 7. dt cast+pad: dbl[:, :48] -> dtb [8192 x 64]
    cast_pad_kernel<<<cdiv(R * 64, 256), 256, 0, stream>>>(dbl, dtb, (int)R, 64, (int)R, 48, 80);
    // 8. delta = softplus(dt @ dt_proj_w^T + b)   [8192 x 1536]
    gemm_bt_kernel<<<dim3(64, 12), 256, 0, stream>>>(dtb, dtwb, (int)R, 1536, 64,
                                                     2, deltab, 1536, 1536, dt_proj_b, nullptr);
    // 9. selective scan -> y bf16
    scan_kernel<<<384, 64, 0, stream>>>(deltab, ub, xzb, dbl, A_log, D_param, yb);
    // 10. out = x + gate * (y @ out_proj_w^T)   [8192 x 768] f32
    gemm_bt_kernel<<<dim3(64, 6), 256, 0, stream>>>(yb, w2b, (int)R, 768, 1536,
                                                    3, (float*)d_out, 768, 768, x, gateb);
}

// Round 2
// 541.311 us; speedup vs baseline: 3.9417x; 3.9417x over previous
//
#include <hip/hip_runtime.h>
#include <hip/hip_bf16.h>
#include <stdint.h>

// Problem constants
#define B_DIM 4
#define L_DIM 2048
#define D_DIM 768
#define DI_DIM 1536
#define DS_DIM 16
#define DR_DIM 48
#define CHUNK 64
#define NCHUNK 32   // L_DIM / CHUNK

typedef __attribute__((ext_vector_type(8))) short bf16x8;   // 8 bf16 = 4 VGPRs (MFMA A/B frag)
typedef __attribute__((ext_vector_type(4))) float f32x4;    // MFMA C/D frag

__device__ inline float bf2f(ushort h) {
    union { uint32_t u; float f; } x; x.u = ((uint32_t)h) << 16; return x.f;
}
__device__ inline ushort f2bf(float f) {
    union { float f; uint32_t u; } x; x.f = f;
    uint32_t r = x.u + 0x7fffu + ((x.u >> 16) & 1u);  // RNE
    return (ushort)(r >> 16);
}
__device__ inline float sigmoidf_(float v) { return 1.f / (1.f + __expf(-v)); }

// ---------------------------------------------------------------------------
// ada = silu(c) @ ada_w.T + ada_b  -> shift/scale/gate  (each [B,768] f32)
// ---------------------------------------------------------------------------
__global__ __launch_bounds__(256) void ada_kernel(
    const float* __restrict__ c, const float* __restrict__ ada_w,
    const float* __restrict__ ada_b,
    float* __restrict__ shiftb, float* __restrict__ scaleb, float* __restrict__ gateb)
{
    __shared__ float lc[2 * D_DIM];  // silu(c[b,:]), 1536 floats
    int b = blockIdx.x / 576;
    int jbase = (blockIdx.x % 576) * 4;
    int tid = threadIdx.x;
    for (int k = tid; k < 2 * D_DIM; k += 256) {
        float cv = c[b * 2 * D_DIM + k];
        lc[k] = cv * sigmoidf_(cv);
    }
    __syncthreads();
    int wave = tid >> 6, lane = tid & 63;
    int j = jbase + wave;
    const float4* wrow = reinterpret_cast<const float4*>(ada_w + (size_t)j * (2 * D_DIM));
    const float4* lc4 = reinterpret_cast<const float4*>(lc);
    float acc = 0.f;
#pragma unroll
    for (int i = 0; i < 6; ++i) {
        float4 w = wrow[lane + 64 * i];
        float4 a = lc4[lane + 64 * i];
        acc += a.x * w.x + a.y * w.y + a.z * w.z + a.w * w.w;
    }
#pragma unroll
    for (int off = 32; off >= 1; off >>= 1) acc += __shfl_xor(acc, off);
    if (lane == 0) {
        acc += ada_b[j];
        if (j < 768)       shiftb[b * 768 + j] = acc;
        else if (j < 1536) scaleb[b * 768 + (j - 768)] = acc;
        else               gateb[b * 768 + (j - 1536)] = acc;
    }
}

// ---------------------------------------------------------------------------
// Generic f32 -> bf16 cast with zero padding.
// ---------------------------------------------------------------------------
__global__ void cast_pad_kernel(const float* __restrict__ src, ushort* __restrict__ dst,
                                int Rd, int Cd, int Rs, int Cs, int src_ld)
{
    int gid = blockIdx.x * 256 + threadIdx.x;
    if (gid >= Rd * Cd) return;
    int r = gid / Cd, cc = gid % Cd;
    float v = (r < Rs && cc < Cs) ? src[(size_t)r * src_ld + cc] : 0.f;
    dst[gid] = f2bf(v);
}

// ---------------------------------------------------------------------------
// LayerNorm + AdaLN modulation -> xm (bf16, [8192,768])
// ---------------------------------------------------------------------------
__global__ __launch_bounds__(256) void ln_mod_kernel(
    const float* __restrict__ x, const float* __restrict__ ln_w, const float* __restrict__ ln_b,
    const float* __restrict__ shiftb, const float* __restrict__ scaleb, ushort* __restrict__ xmb)
{
    int row = blockIdx.x;          // b*2048 + l
    int bb = row >> 11;
    int tid = threadIdx.x;
    const float* xr = x + (size_t)row * D_DIM;
    float v0 = xr[tid], v1 = xr[tid + 256], v2 = xr[tid + 512];
    float s1 = v0 + v1 + v2;
    float s2 = v0 * v0 + v1 * v1 + v2 * v2;
#pragma unroll
    for (int off = 32; off >= 1; off >>= 1) { s1 += __shfl_xor(s1, off); s2 += __shfl_xor(s2, off); }
    __shared__ float red[8];
    int wave = tid >> 6, lane = tid & 63;
    if (lane == 0) { red[wave] = s1; red[4 + wave] = s2; }
    __syncthreads();
    s1 = red[0] + red[1] + red[2] + red[3];
    s2 = red[4] + red[5] + red[6] + red[7];
    float mu = s1 * (1.f / 768.f);
    float var = s2 * (1.f / 768.f) - mu * mu;
    float rs = rsqrtf(var + 1e-5f);
    const float* sh = shiftb + bb * D_DIM;
    const float* sc = scaleb + bb * D_DIM;
    ushort* orow = xmb + (size_t)row * D_DIM;
#pragma unroll
    for (int r = 0; r < 3; ++r) {
        int j = tid + r * 256;
        float xv = (r == 0 ? v0 : (r == 1 ? v1 : v2));
        float xn = (xv - mu) * rs * ln_w[j] + ln_b[j];
        orow[j] = f2bf(xn * (1.f + sc[j]) + sh[j]);
    }
}

// ---------------------------------------------------------------------------
// bf16 MFMA GEMM:  C[M,N] = A[M,K] @ B[N,K]^T  (128x128 tile, 4 waves 2x2)
// ---------------------------------------------------------------------------
__global__ __launch_bounds__(256, 2) void gemm_bt_kernel(
    const ushort* __restrict__ A, const ushort* __restrict__ B,
    int M, int N, int K,
    int mode, void* __restrict__ Cout, int ldc, int Nstore,
    const float* __restrict__ aux0, const float* __restrict__ aux1)
{
    __shared__ ushort ldsA[128 * 40];  // row stride 40 (pad 8)
    __shared__ ushort ldsB[128 * 40];
    int m0 = blockIdx.x * 128, n0 = blockIdx.y * 128;
    int tid = threadIdx.x;
    int wave = tid >> 6, lane = tid & 63;
    int wr = wave >> 1, wc = wave & 1;
    int quad = lane >> 4, lr = lane & 15;

    f32x4 zero4 = {0.f, 0.f, 0.f, 0.f};
    f32x4 acc[4][4];
#pragma unroll
    for (int i = 0; i < 4; ++i)
#pragma unroll
        for (int j = 0; j < 4; ++j) acc[i][j] = zero4;

    for (int k0 = 0; k0 < K; k0 += 32) {
        __syncthreads();
#pragma unroll
        for (int rr = 0; rr < 2; ++rr) {
            int c = tid + rr * 256;       // 0..511
            int row = c >> 2, kp = c & 3;
            uint4 va = *reinterpret_cast<const uint4*>(A + (size_t)(m0 + row) * K + k0 + kp * 8);
            *reinterpret_cast<uint4*>(&ldsA[row * 40 + kp * 8]) = va;
            uint4 vb = *reinterpret_cast<const uint4*>(B + (size_t)(n0 + row) * K + k0 + kp * 8);
            *reinterpret_cast<uint4*>(&ldsB[row * 40 + kp * 8]) = vb;
        }
        __syncthreads();
        bf16x8 af[4], bfr[4];
#pragma unroll
        for (int i = 0; i < 4; ++i)
            af[i] = *reinterpret_cast<const bf16x8*>(&ldsA[(wr * 64 + i * 16 + lr) * 40 + quad * 8]);
#pragma unroll
        for (int j = 0; j < 4; ++j)
            bfr[j] = *reinterpret_cast<const bf16x8*>(&ldsB[(wc * 64 + j * 16 + lr) * 40 + quad * 8]);
#pragma unroll
        for (int i = 0; i < 4; ++i)
#pragma unroll
            for (int j = 0; j < 4; ++j)
                acc[i][j] = __builtin_amdgcn_mfma_f32_16x16x32_bf16(af[i], bfr[j], acc[i][j], 0, 0, 0);
    }

    // epilogue: C/D layout col=lane&15, row=quad*4+reg  [m89-verified]
#pragma unroll
    for (int i = 0; i < 4; ++i) {
#pragma unroll
        for (int j = 0; j < 4; ++j) {
#pragma unroll
            for (int r = 0; r < 4; ++r) {
                int grow = m0 + wr * 64 + i * 16 + quad * 4 + r;
                int gcol = n0 + wc * 64 + j * 16 + lr;
                float v = acc[i][j][r];
                if (mode == 0) {
                    ((ushort*)Cout)[(size_t)grow * ldc + gcol] = f2bf(v);
                } else if (mode == 1) {
                    if (gcol < Nstore) ((float*)Cout)[(size_t)grow * ldc + gcol] = v;
                } else if (mode == 2) {
                    float t = v + aux0[gcol];
                    float sp = (t > 20.f) ? t : log1pf(__expf(t));
                    ((ushort*)Cout)[(size_t)grow * ldc + gcol] = f2bf(sp);
                } else {
                    int bb = grow >> 11;
                    ((float*)Cout)[(size_t)grow * ldc + gcol] =
                        aux0[(size_t)grow * ldc + gcol] + aux1[bb * ldc + gcol] * v;
                }
            }
        }
    }
}

// ---------------------------------------------------------------------------
// depthwise causal conv (K=4) + bias + silu -> u (bf16 [8192,1536])
// ---------------------------------------------------------------------------
__global__ void conv_silu_kernel(const ushort* __restrict__ xz, const float* __restrict__ conv_w,
                                 const float* __restrict__ conv_b, ushort* __restrict__ u)
{
    int gid = blockIdx.x * 256 + threadIdx.x;   // < 12582912
    int ch = gid % DI_DIM;
    int bl = gid / DI_DIM;
    int l = bl & (L_DIM - 1);
    int bb = bl >> 11;
    float acc = conv_b[ch];
#pragma unroll
    for (int k = 0; k < 4; ++k) {
        int ll = l - 3 + k;
        if (ll >= 0)
            acc += bf2f(xz[((size_t)bb * L_DIM + ll) * 3072 + ch]) * conv_w[ch * 4 + k];
    }
    u[(size_t)bl * DI_DIM + ch] = f2bf(acc * sigmoidf_(acc));
}

// ---------------------------------------------------------------------------
// Chunked selective scan, pass 1: per-(b,chunk,d) local scan with h0=0.
// Emits chunk-final h[16] and per-state decay product P[16].
// grid dim3(6, NCHUNK, B), block 256 (d = blockIdx.x*256+tid)
// ---------------------------------------------------------------------------
__global__ __launch_bounds__(256) void scan_part1(
    const ushort* __restrict__ delta, const ushort* __restrict__ u,
    const float* __restrict__ dbl, const float* __restrict__ A_log,
    float* __restrict__ hbuf, float* __restrict__ Pbuf)
{
    int tid = threadIdx.x;
    int d = blockIdx.x * 256 + tid;
    int chunk = blockIdx.y;
    int b = blockIdx.z;
    __shared__ float lsB[CHUNK][16];
    {
        int li = tid >> 2, g = tid & 3;
        const float* src = dbl + ((size_t)b * L_DIM + chunk * CHUNK + li) * 80 + 48 + g * 4;
        float4 v = *reinterpret_cast<const float4*>(src);
        lsB[li][g * 4 + 0] = v.x; lsB[li][g * 4 + 1] = v.y;
        lsB[li][g * 4 + 2] = v.z; lsB[li][g * 4 + 3] = v.w;
    }
    __syncthreads();
    float Ad[16];
#pragma unroll
    for (int s = 0; s < 16; ++s) Ad[s] = -__expf(A_log[d * DS_DIM + s]);
    float h[16], P[16];
#pragma unroll
    for (int s = 0; s < 16; ++s) { h[s] = 0.f; P[s] = 1.f; }
    size_t rowbase = (size_t)b * L_DIM + chunk * CHUNK;
    for (int li = 0; li < CHUNK; ++li) {
        size_t idx = (rowbase + li) * DI_DIM + d;
        float dt = bf2f(delta[idx]);
        float du = dt * bf2f(u[idx]);
#pragma unroll
        for (int s = 0; s < 16; ++s) {
            float dA = __expf(dt * Ad[s]);
            h[s] = dA * h[s] + du * lsB[li][s];
            P[s] *= dA;
        }
    }
    size_t bo = (((size_t)b * NCHUNK + chunk) * DI_DIM + d) * 16;
#pragma unroll
    for (int s = 0; s < 16; ++s) { hbuf[bo + s] = h[s]; Pbuf[bo + s] = P[s]; }
}

// ---------------------------------------------------------------------------
// Pass 2: serial over chunk boundaries (32 steps), parallel over (b,d,s).
// After this, Pbuf[b,c,d,s] holds h_start for chunk c.
// ---------------------------------------------------------------------------
__global__ __launch_bounds__(256) void scan_part2(
    const float* __restrict__ hbuf, float* __restrict__ Pbuf)
{
    int gid = blockIdx.x * 256 + threadIdx.x;  // < B*DI*16 = 98304
    int b = gid / (DI_DIM * DS_DIM);
    int rem = gid % (DI_DIM * DS_DIM);         // d*16+s
    float hc = 0.f;
    for (int c = 0; c < NCHUNK; ++c) {
        size_t o = ((size_t)b * NCHUNK + c) * (DI_DIM * DS_DIM) + rem;
        float hl = hbuf[o];
        float P  = Pbuf[o];
        Pbuf[o] = hc;        // h at chunk start
        hc = P * hc + hl;
    }
}

// ---------------------------------------------------------------------------
// Pass 3: re-scan each chunk from exact h_start; y = C.h; fuse +u*D, *silu(z).
// ---------------------------------------------------------------------------
__global__ __launch_bounds__(256) void scan_part3(
    const ushort* __restrict__ delta, const ushort* __restrict__ u,
    const ushort* __restrict__ xz, const float* __restrict__ dbl,
    const float* __restrict__ A_log, const float* __restrict__ D_param,
    const float* __restrict__ hstart, ushort* __restrict__ ybuf)
{
    int tid = threadIdx.x;
    int d = blockIdx.x * 256 + tid;
    int chunk = blockIdx.y;
    int b = blockIdx.z;
    __shared__ float lsB[CHUNK][16];
    __shared__ float lsC[CHUNK][16];
    {
        int li = tid >> 2, g = tid & 3;
        const float* src = dbl + ((size_t)b * L_DIM + chunk * CHUNK + li) * 80 + 48;
        float4 vB = *reinterpret_cast<const float4*>(src + g * 4);
        float4 vC = *reinterpret_cast<const float4*>(src + 16 + g * 4);
        lsB[li][g * 4 + 0] = vB.x; lsB[li][g * 4 + 1] = vB.y;
        lsB[li][g * 4 + 2] = vB.z; lsB[li][g * 4 + 3] = vB.w;
        lsC[li][g * 4 + 0] = vC.x; lsC[li][g * 4 + 1] = vC.y;
        lsC[li][g * 4 + 2] = vC.z; lsC[li][g * 4 + 3] = vC.w;
    }
    __syncthreads();
    float Ad[16];
#pragma unroll
    for (int s = 0; s < 16; ++s) Ad[s] = -__expf(A_log[d * DS_DIM + s]);
    float Dp = D_param[d];
    size_t bo = (((size_t)b * NCHUNK + chunk) * DI_DIM + d) * 16;
    float h[16];
#pragma unroll
    for (int s = 0; s < 16; ++s) h[s] = hstart[bo + s];
    size_t rowbase = (size_t)b * L_DIM + chunk * CHUNK;
    for (int li = 0; li < CHUNK; ++li) {
        size_t idx = (rowbase + li) * DI_DIM + d;
        float dt = bf2f(delta[idx]);
        float ut = bf2f(u[idx]);
        float zt = bf2f(xz[(rowbase + li) * 3072 + DI_DIM + d]);
        float du = dt * ut;
        float y = 0.f;
#pragma unroll
        for (int s = 0; s < 16; ++s) {
            float dA = __expf(dt * Ad[s]);
            h[s] = dA * h[s] + du * lsB[li][s];
            y += h[s] * lsC[li][s];
        }
        float yy = (y + ut * Dp) * (zt * sigmoidf_(zt));
        ybuf[idx] = f2bf(yy);
    }
}

// ---------------------------------------------------------------------------
extern "C" void kernel_launch(void* const* d_in, const int* in_sizes, int n_in,
                              void* d_out, int out_size, void* d_ws, size_t ws_size,
                              hipStream_t stream) {
    (void)in_sizes; (void)n_in; (void)out_size;
    const float* x         = (const float*)d_in[0];
    const float* c         = (const float*)d_in[1];
    const float* ln_w      = (const float*)d_in[2];
    const float* ln_b      = (const float*)d_in[3];
    const float* ada_w     = (const float*)d_in[4];
    const float* ada_b     = (const float*)d_in[5];
    const float* in_proj_w = (const float*)d_in[6];
    const float* conv_w    = (const float*)d_in[7];
    const float* conv_b    = (const float*)d_in[8];
    const float* x_proj_w  = (const float*)d_in[9];
    const float* dt_proj_w = (const float*)d_in[10];
    const float* dt_proj_b = (const float*)d_in[11];
    const float* A_log     = (const float*)d_in[12];
    const float* D_param   = (const float*)d_in[13];
    const float* out_proj_w= (const float*)d_in[14];

    char* base = (char*)d_ws;
    size_t off = 0;
    auto alloc = [&](size_t bytes) { size_t o = off; off = (off + bytes + 255) & ~(size_t)255; return o; };
    const size_t R = (size_t)B_DIM * L_DIM;           // 8192 rows

    size_t o_shift = alloc(B_DIM * D_DIM * 4);
    size_t o_scale = alloc(B_DIM * D_DIM * 4);
    size_t o_gate  = alloc(B_DIM * D_DIM * 4);
    size_t o_xmb   = alloc(R * D_DIM * 2);            // bf16 xm
    size_t o_w1b   = alloc((size_t)3072 * 768 * 2);   // in_proj bf16
    size_t o_w2b   = alloc((size_t)768 * 1536 * 2);   // out_proj bf16
    size_t o_xwb   = alloc((size_t)128 * 1536 * 2);   // x_proj bf16, N-padded 80->128
    size_t o_dtwb  = alloc((size_t)1536 * 64 * 2);    // dt_proj bf16, K-padded 48->64
    size_t o_xzb   = alloc(R * 3072 * 2);             // xz bf16
    size_t o_ub    = alloc(R * DI_DIM * 2);           // u bf16
    size_t o_dbl   = alloc(R * 80 * 4);               // dbl f32
    size_t o_dtb   = alloc(R * 64 * 2);               // dt bf16, K-padded
    size_t o_delta = alloc(R * DI_DIM * 2);           // delta bf16
    size_t o_yb    = alloc(R * DI_DIM * 2);           // y bf16
    size_t o_hb    = alloc((size_t)B_DIM * NCHUNK * DI_DIM * 16 * 4);  // 12.6 MB
    size_t o_pb    = alloc((size_t)B_DIM * NCHUNK * DI_DIM * 16 * 4);  // 12.6 MB
    if (ws_size < off) return;

    float*  shiftb = (float*)(base + o_shift);
    float*  scaleb = (float*)(base + o_scale);
    float*  gateb  = (float*)(base + o_gate);
    ushort* xmb    = (ushort*)(base + o_xmb);
    ushort* w1b    = (ushort*)(base + o_w1b);
    ushort* w2b    = (ushort*)(base + o_w2b);
    ushort* xwb    = (ushort*)(base + o_xwb);
    ushort* dtwb   = (ushort*)(base + o_dtwb);
    ushort* xzb    = (ushort*)(base + o_xzb);
    ushort* ub     = (ushort*)(base + o_ub);
    float*  dbl    = (float*)(base + o_dbl);
    ushort* dtb    = (ushort*)(base + o_dtb);
    ushort* deltab = (ushort*)(base + o_delta);
    ushort* yb     = (ushort*)(base + o_yb);
    float*  hb     = (float*)(base + o_hb);
    float*  pb     = (float*)(base + o_pb);

    auto cdiv = [](size_t a, size_t b) { return (int)((a + b - 1) / b); };

    // 1. ada -> shift/scale/gate
    ada_kernel<<<2304, 256, 0, stream>>>(c, ada_w, ada_b, shiftb, scaleb, gateb);
    // 2. weight casts
    cast_pad_kernel<<<cdiv(3072 * 768, 256), 256, 0, stream>>>(in_proj_w, w1b, 3072, 768, 3072, 768, 768);
    cast_pad_kernel<<<cdiv(768 * 1536, 256), 256, 0, stream>>>(out_proj_w, w2b, 768, 1536, 768, 1536, 1536);
    cast_pad_kernel<<<cdiv(128 * 1536, 256), 256, 0, stream>>>(x_proj_w, xwb, 128, 1536, 80, 1536, 1536);
    cast_pad_kernel<<<cdiv(1536 * 64, 256), 256, 0, stream>>>(dt_proj_w, dtwb, 1536, 64, 1536, 48, 48);
    // 3. LayerNorm + modulation -> xm bf16
    ln_mod_kernel<<<(int)R, 256, 0, stream>>>(x, ln_w, ln_b, shiftb, scaleb, xmb);
    // 4. xz = xm @ in_proj_w^T   [8192 x 3072]
    gemm_bt_kernel<<<dim3(64, 24), 256, 0, stream>>>(xmb, w1b, (int)R, 3072, 768,
                                                     0, xzb, 3072, 3072, nullptr, nullptr);
    // 5. depthwise conv + silu -> u
    conv_silu_kernel<<<cdiv(R * DI_DIM, 256), 256, 0, stream>>>(xzb, conv_w, conv_b, ub);
    // 6. dbl = u @ x_proj_w^T    [8192 x 80]  (N padded to 128)
    gemm_bt_kernel<<<dim3(64, 1), 256, 0, stream>>>(ub, xwb, (int)R, 128, 1536,
                                                    1, dbl, 80, 80, nullptr, nullptr);
    // 7. dt cast+pad: dbl[:, :48] -> dtb [8192 x 64]
    cast_pad_kernel<<<cdiv(R * 64, 256), 256, 0, stream>>>(dbl, dtb, (int)R, 64, (int)R, 48, 80);
    // 8. delta = softplus(dt @ dt_proj_w^T + b)   [8192 x 1536]
    gemm_bt_kernel<<<dim3(64, 12), 256, 0, stream>>>(dtb, dtwb, (int)R, 1536, 64,
                                                     2, deltab, 1536, 1536, dt_proj_b, nullptr);
    // 9. chunked selective scan -> y bf16
    scan_part1<<<dim3(6, NCHUNK, B_DIM), 256, 0, stream>>>(deltab, ub, dbl, A_log, hb, pb);
    scan_part2<<<cdiv((size_t)B_DIM * DI_DIM * DS_DIM, 256), 256, 0, stream>>>(hb, pb);
    scan_part3<<<dim3(6, NCHUNK, B_DIM), 256, 0, stream>>>(deltab, ub, xzb, dbl, A_log, D_param, pb, yb);
    // 10. out = x + gate * (y @ out_proj_w^T)   [8192 x 768] f32
    gemm_bt_kernel<<<dim3(64, 6), 256, 0, stream>>>(yb, w2b, (int)R, 768, 1536,
                                                    3, (float*)d_out, 768, 768, x, gateb);
}